// Round 1
// baseline (64.787 us; speedup 1.0000x reference)
//
#include <hip/hip_runtime.h>
#include <math.h>

// N=8192 oscillators. Reference is O(N^2) (pairwise cos/sin coupling), but
// cos(pi-pj)/sin(pi-pj) factorization reduces it to 4 global scalar sums:
//   A = sum cos(pj)*xj, B = sum sin(pj)*xj, C = sum cos(pj)*yj, D = sum sin(pj)*yj
//   sum_x[i] = ci*(A+D) + si*(B-C);  sum_y[i] = si*(A+D) + ci*(C-B)
// Single block (1024 threads x 8 elems) => one dispatch, deterministic LDS
// reduction, no scratch, no atomics. Problem is launch-latency bound.

#define NOSC 8192
#define NTHREADS 1024
#define PER_THREAD (NOSC / NTHREADS)  // 8

__global__ __launch_bounds__(NTHREADS, 1) void nacpg_kernel(
    const float* __restrict__ phase,
    const float* __restrict__ w,
    const float* __restrict__ xy,
    const float* __restrict__ xy_dot_old,
    float* __restrict__ out)
{
    constexpr float COUP  = 0.08f;
    constexpr float ALPHA = 0.45f;
    constexpr float DT    = 0.01f;
    constexpr float DIFF  = 10.0f;

    const int tid = threadIdx.x;

    float c[PER_THREAD], s[PER_THREAD], x[PER_THREAD], y[PER_THREAD];
    float sA = 0.f, sB = 0.f, sC = 0.f, sD = 0.f;

    #pragma unroll
    for (int k = 0; k < PER_THREAD; ++k) {
        const int i = tid + k * NTHREADS;
        const float p = phase[i];
        const float2 v = reinterpret_cast<const float2*>(xy)[i];
        x[k] = v.x; y[k] = v.y;
        float ss, cc;
        sincosf(p, &ss, &cc);   // precise path; phase ~ N(0,1), cheap enough
        c[k] = cc; s[k] = ss;
        sA = fmaf(cc, v.x, sA);
        sB = fmaf(ss, v.x, sB);
        sC = fmaf(cc, v.y, sC);
        sD = fmaf(ss, v.y, sD);
    }

    // 64-lane butterfly reduce (wave = 64 on CDNA4)
    #pragma unroll
    for (int off = 32; off >= 1; off >>= 1) {
        sA += __shfl_xor(sA, off);
        sB += __shfl_xor(sB, off);
        sC += __shfl_xor(sC, off);
        sD += __shfl_xor(sD, off);
    }

    __shared__ float red[4][NTHREADS / 64];
    const int wave = tid >> 6;
    const int lane = tid & 63;
    if (lane == 0) {
        red[0][wave] = sA; red[1][wave] = sB;
        red[2][wave] = sC; red[3][wave] = sD;
    }
    __syncthreads();

    float A = 0.f, B = 0.f, C = 0.f, D = 0.f;
    #pragma unroll
    for (int wv = 0; wv < NTHREADS / 64; ++wv) {
        A += red[0][wv]; B += red[1][wv];
        C += red[2][wv]; D += red[3][wv];
    }

    const float AD = A + D;         // coefficient of ci in sum_x, si in sum_y
    const float BC = B - C;         // coefficient of si in sum_x
    const float CB = C - B;         // coefficient of ci in sum_y
    const float inv_deg = 1.0f / (float)(NOSC - 1);

    float2* __restrict__ out_xy  = reinterpret_cast<float2*>(out);
    float2* __restrict__ out_xyd = reinterpret_cast<float2*>(out + 2 * NOSC);
    float*  __restrict__ out_yu  = out + 4 * NOSC;

    #pragma unroll
    for (int k = 0; k < PER_THREAD; ++k) {
        const int i = tid + k * NTHREADS;
        const float ci = c[k], si = s[k];
        const float xi = x[k], yi = y[k];

        const float sum_x = ci * AD + si * BC;
        const float sum_y = si * AD + ci * CB;
        const float coup_x = COUP * (sum_x - xi) * inv_deg;
        const float coup_y = COUP * (sum_y - yi) * inv_deg;

        const float r2 = xi * xi + yi * yi;
        const float a  = ALPHA * (1.0f - r2);
        const float wi = w[i];

        float xdot = a * xi - wi * yi + coup_x;
        float ydot = wi * xi + a * yi + coup_y;

        const float2 old = reinterpret_cast<const float2*>(xy_dot_old)[i];
        xdot = fminf(fmaxf(xdot, old.x - DIFF), old.x + DIFF);
        ydot = fminf(fmaxf(ydot, old.y - DIFF), old.y + DIFF);

        const float nx = xi + DT * xdot;
        const float ny = yi + DT * ydot;

        out_xy[i]  = make_float2(nx, ny);
        out_xyd[i] = make_float2(xdot, ydot);
        out_yu[i]  = fminf(fmaxf(ny, -1.0f), 1.0f);
    }
}

extern "C" void kernel_launch(void* const* d_in, const int* in_sizes, int n_in,
                              void* d_out, int out_size, void* d_ws, size_t ws_size,
                              hipStream_t stream) {
    const float* phase      = (const float*)d_in[0];
    const float* w          = (const float*)d_in[1];
    const float* xy         = (const float*)d_in[2];
    const float* xy_dot_old = (const float*)d_in[3];
    float* out = (float*)d_out;

    nacpg_kernel<<<1, NTHREADS, 0, stream>>>(phase, w, xy, xy_dot_old, out);
}

// Round 2
// 61.340 us; speedup vs baseline: 1.0562x; 1.0562x over previous
//
#include <hip/hip_runtime.h>
#include <math.h>

// N=8192 oscillators. O(N^2) pairwise coupling collapses algebraically:
//   cos(pi-pj) = ci*cj + si*sj ;  sin(pi-pj) = si*cj - ci*sj
//   A=sum cj*xj, B=sum sj*xj, C=sum cj*yj, D=sum sj*yj
//   sum_x[i] = ci*(A+D) + si*(B-C);  sum_y[i] = si*(A+D) + ci*(C-B)
// Two tiny dispatches (deterministic, no atomics), spread over 64 CUs:
//   k1: per-block partial sums -> 64 float4 partials in d_ws
//   k2: butterfly-reduce partials in-wave, then elementwise ODE step.
// Latency-bound; ~350 KB total I/O.

#define NOSC 8192
#define NTHR 128                 // 2 waves/block
#define NBLK (NOSC / NTHR)       // 64 blocks == 64 partials == 64 lanes

__global__ __launch_bounds__(NTHR, 1) void nacpg_partial(
    const float* __restrict__ phase,
    const float* __restrict__ xy,
    float4* __restrict__ part)
{
    const int i = blockIdx.x * NTHR + threadIdx.x;
    const float p = phase[i];
    const float2 v = reinterpret_cast<const float2*>(xy)[i];
    float s, c;
    __sincosf(p, &s, &c);

    float A = c * v.x;
    float B = s * v.x;
    float C = c * v.y;
    float D = s * v.y;

    #pragma unroll
    for (int off = 32; off >= 1; off >>= 1) {
        A += __shfl_xor(A, off);
        B += __shfl_xor(B, off);
        C += __shfl_xor(C, off);
        D += __shfl_xor(D, off);
    }

    __shared__ float4 red[NTHR / 64];
    const int wave = threadIdx.x >> 6;
    const int lane = threadIdx.x & 63;
    if (lane == 0) red[wave] = make_float4(A, B, C, D);
    __syncthreads();
    if (threadIdx.x == 0) {
        float4 a = red[0], b = red[1];
        part[blockIdx.x] = make_float4(a.x + b.x, a.y + b.y, a.z + b.z, a.w + b.w);
    }
}

__global__ __launch_bounds__(NTHR, 1) void nacpg_main(
    const float* __restrict__ phase,
    const float* __restrict__ w,
    const float* __restrict__ xy,
    const float* __restrict__ xy_dot_old,
    const float4* __restrict__ part,
    float* __restrict__ out)
{
    constexpr float COUP  = 0.08f;
    constexpr float ALPHA = 0.45f;
    constexpr float DT    = 0.01f;
    constexpr float DIFF  = 10.0f;

    const int i    = blockIdx.x * NTHR + threadIdx.x;
    const int lane = threadIdx.x & 63;

    // Issue all per-i loads first so they overlap the reduction chain.
    const float p       = phase[i];
    const float wi      = w[i];
    const float2 v      = reinterpret_cast<const float2*>(xy)[i];
    const float2 old    = reinterpret_cast<const float2*>(xy_dot_old)[i];

    // Each lane owns one of the 64 block-partials; butterfly gives all lanes
    // the global sums.
    float4 pp = part[lane];
    float A = pp.x, B = pp.y, C = pp.z, D = pp.w;
    #pragma unroll
    for (int off = 32; off >= 1; off >>= 1) {
        A += __shfl_xor(A, off);
        B += __shfl_xor(B, off);
        C += __shfl_xor(C, off);
        D += __shfl_xor(D, off);
    }

    const float AD = A + D;
    const float BC = B - C;
    const float CB = C - B;
    const float inv_deg = 1.0f / (float)(NOSC - 1);

    float s, c;
    __sincosf(p, &s, &c);

    const float xi = v.x, yi = v.y;
    const float sum_x = c * AD + s * BC;
    const float sum_y = s * AD + c * CB;
    const float coup_x = COUP * (sum_x - xi) * inv_deg;
    const float coup_y = COUP * (sum_y - yi) * inv_deg;

    const float r2 = xi * xi + yi * yi;
    const float a  = ALPHA * (1.0f - r2);

    float xdot = a * xi - wi * yi + coup_x;
    float ydot = wi * xi + a * yi + coup_y;

    xdot = fminf(fmaxf(xdot, old.x - DIFF), old.x + DIFF);
    ydot = fminf(fmaxf(ydot, old.y - DIFF), old.y + DIFF);

    const float nx = xi + DT * xdot;
    const float ny = yi + DT * ydot;

    reinterpret_cast<float2*>(out)[i]             = make_float2(nx, ny);
    reinterpret_cast<float2*>(out + 2 * NOSC)[i]  = make_float2(xdot, ydot);
    out[4 * NOSC + i] = fminf(fmaxf(ny, -1.0f), 1.0f);
}

extern "C" void kernel_launch(void* const* d_in, const int* in_sizes, int n_in,
                              void* d_out, int out_size, void* d_ws, size_t ws_size,
                              hipStream_t stream) {
    const float* phase      = (const float*)d_in[0];
    const float* w          = (const float*)d_in[1];
    const float* xy         = (const float*)d_in[2];
    const float* xy_dot_old = (const float*)d_in[3];
    float* out   = (float*)d_out;
    float4* part = (float4*)d_ws;   // 64 * 16 B = 1 KB of scratch

    nacpg_partial<<<NBLK, NTHR, 0, stream>>>(phase, xy, part);
    nacpg_main<<<NBLK, NTHR, 0, stream>>>(phase, w, xy, xy_dot_old, part, out);
}

// Round 3
// 60.412 us; speedup vs baseline: 1.0724x; 1.0154x over previous
//
#include <hip/hip_runtime.h>
#include <math.h>

// N=8192 oscillators. O(N^2) pairwise coupling collapses algebraically:
//   cos(pi-pj) = ci*cj + si*sj ;  sin(pi-pj) = si*cj - ci*sj
//   A=sum cj*xj, B=sum sj*xj, C=sum cj*yj, D=sum sj*yj
//   sum_x[i] = ci*(A+D) + si*(B-C);  sum_y[i] = si*(A+D) + ci*(C-B)
//
// SINGLE dispatch: each of 64 blocks redundantly computes the full 4-scalar
// reduction (96 KB read/block, L2-absorbed; 32 __sincosf/thread), then does
// its 128-element slice of the elementwise ODE step. No scratch, no atomics,
// no inter-kernel dependency. Timed iteration is dominated by the harness's
// 268 MB d_ws re-poison fill (~39.4 us) which we cannot control.

#define NOSC 8192
#define NTHR 256
#define NBLK 64
#define EPB  (NOSC / NBLK)    // 128 elementwise elems per block

__global__ __launch_bounds__(NTHR, 1) void nacpg_fused(
    const float* __restrict__ phase,
    const float* __restrict__ w,
    const float* __restrict__ xy,
    const float* __restrict__ xy_dot_old,
    float* __restrict__ out)
{
    constexpr float COUP  = 0.08f;
    constexpr float ALPHA = 0.45f;
    constexpr float DT    = 0.01f;
    constexpr float DIFF  = 10.0f;

    const int t = threadIdx.x;

    // ---- redundant full reduction: all 8192 elems, float4-vectorized ----
    const float4* __restrict__ ph4 = reinterpret_cast<const float4*>(phase); // 2048
    const float4* __restrict__ xy4 = reinterpret_cast<const float4*>(xy);    // 4096

    float A = 0.f, B = 0.f, C = 0.f, D = 0.f;

    auto acc = [&](float p, float vx, float vy) {
        float s, c;
        __sincosf(p, &s, &c);
        A = fmaf(c, vx, A);
        B = fmaf(s, vx, B);
        C = fmaf(c, vy, C);
        D = fmaf(s, vy, D);
    };

    #pragma unroll
    for (int k = 0; k < NOSC / 4 / NTHR; ++k) {   // 8 iterations
        const int idx = t + k * NTHR;             // float4 index, 0..2047
        const float4 p = ph4[idx];
        const float4 a = xy4[2 * idx];            // xy[4idx+0], xy[4idx+1]
        const float4 b = xy4[2 * idx + 1];        // xy[4idx+2], xy[4idx+3]
        acc(p.x, a.x, a.y);
        acc(p.y, a.z, a.w);
        acc(p.z, b.x, b.y);
        acc(p.w, b.z, b.w);
    }

    // wave64 butterfly
    #pragma unroll
    for (int off = 32; off >= 1; off >>= 1) {
        A += __shfl_xor(A, off);
        B += __shfl_xor(B, off);
        C += __shfl_xor(C, off);
        D += __shfl_xor(D, off);
    }

    // cross-wave via LDS (4 waves)
    __shared__ float4 red[NTHR / 64];
    const int wave = t >> 6;
    const int lane = t & 63;
    if (lane == 0) red[wave] = make_float4(A, B, C, D);
    __syncthreads();
    {
        const float4 r0 = red[0], r1 = red[1], r2 = red[2], r3 = red[3];
        A = r0.x + r1.x + r2.x + r3.x;
        B = r0.y + r1.y + r2.y + r3.y;
        C = r0.z + r1.z + r2.z + r3.z;
        D = r0.w + r1.w + r2.w + r3.w;
    }

    const float AD = A + D;
    const float BC = B - C;
    const float CB = C - B;
    const float inv_deg = 1.0f / (float)(NOSC - 1);

    // ---- elementwise slice: 128 elems per block, threads 0..127 ----
    if (t < EPB) {
        const int i = blockIdx.x * EPB + t;

        const float p    = phase[i];
        const float wi   = w[i];
        const float2 v   = reinterpret_cast<const float2*>(xy)[i];
        const float2 old = reinterpret_cast<const float2*>(xy_dot_old)[i];

        float s, c;
        __sincosf(p, &s, &c);

        const float xi = v.x, yi = v.y;
        const float sum_x = c * AD + s * BC;
        const float sum_y = s * AD + c * CB;
        const float coup_x = COUP * (sum_x - xi) * inv_deg;
        const float coup_y = COUP * (sum_y - yi) * inv_deg;

        const float r2 = xi * xi + yi * yi;
        const float a  = ALPHA * (1.0f - r2);

        float xdot = a * xi - wi * yi + coup_x;
        float ydot = wi * xi + a * yi + coup_y;

        xdot = fminf(fmaxf(xdot, old.x - DIFF), old.x + DIFF);
        ydot = fminf(fmaxf(ydot, old.y - DIFF), old.y + DIFF);

        const float nx = xi + DT * xdot;
        const float ny = yi + DT * ydot;

        reinterpret_cast<float2*>(out)[i]            = make_float2(nx, ny);
        reinterpret_cast<float2*>(out + 2 * NOSC)[i] = make_float2(xdot, ydot);
        out[4 * NOSC + i] = fminf(fmaxf(ny, -1.0f), 1.0f);
    }
}

extern "C" void kernel_launch(void* const* d_in, const int* in_sizes, int n_in,
                              void* d_out, int out_size, void* d_ws, size_t ws_size,
                              hipStream_t stream) {
    const float* phase      = (const float*)d_in[0];
    const float* w          = (const float*)d_in[1];
    const float* xy         = (const float*)d_in[2];
    const float* xy_dot_old = (const float*)d_in[3];
    float* out = (float*)d_out;

    nacpg_fused<<<NBLK, NTHR, 0, stream>>>(phase, w, xy, xy_dot_old, out);
}